// Round 1
// baseline (309.096 us; speedup 1.0000x reference)
//
#include <hip/hip_runtime.h>
#include <hip/hip_bf16.h>

#define NE 1000000
#define NN 100000
#define NWT 15625  // NE / 64 edges per wave-tile

typedef __attribute__((ext_vector_type(8))) short bf16x8;
typedef __attribute__((ext_vector_type(4))) float f32x4;

__device__ __forceinline__ unsigned short f2bf(float f) {
  // round-to-nearest-even f32 -> bf16
  unsigned u = __builtin_bit_cast(unsigned, f);
  u += 0x7fffu + ((u >> 16) & 1u);
  return (unsigned short)(u >> 16);
}

// ---------------------------------------------------------------------------
// Prep 1: swizzle W1/W2 (f32 row-major [K][N]) into MFMA B-fragment order:
//   frag for (n-tile nt, k-block kb): lane l holds B[kb*32 + (l>>4)*8 + j][nt*16 + (l&15)], j=0..7
//   stored at fw[((nt*NKB + kb)*64 + l)*8 + j]  -> per-lane 16B contiguous, wave-coalesced 1KB
// ---------------------------------------------------------------------------
__global__ void prep_weights(const float* __restrict__ W1, const float* __restrict__ W2,
                             unsigned short* __restrict__ fw1, unsigned short* __restrict__ fw2) {
  int tid = blockIdx.x * 256 + threadIdx.x;
  if (tid < 32768) {  // W1: [256][128], 8 n-tiles x 8 k-blocks
    int j = tid & 7, l = (tid >> 3) & 63, kb = (tid >> 9) & 7, nt = tid >> 12;
    fw1[tid] = f2bf(W1[(kb * 32 + (l >> 4) * 8 + j) * 128 + nt * 16 + (l & 15)]);
  } else {            // W2: [128][64], 4 n-tiles x 4 k-blocks
    int t = tid - 32768;
    int j = t & 7, l = (t >> 3) & 63, kb = (t >> 9) & 3, nt = t >> 11;
    fw2[t] = f2bf(W2[(kb * 32 + (l >> 4) * 8 + j) * 64 + nt * 16 + (l & 15)]);
  }
}

// Prep 2: z f32 [100000][128] -> bf16 (halves gather bytes, removes per-frag cvt)
__global__ void prep_z(const float4* __restrict__ z4, ushort4* __restrict__ zb4) {
  int tid = blockIdx.x * 256 + threadIdx.x;
  if (tid >= NN * 32) return;  // 12.8e6 / 4
  float4 v = z4[tid];
  ushort4 o;
  o.x = f2bf(v.x); o.y = f2bf(v.y); o.z = f2bf(v.z); o.w = f2bf(v.w);
  zb4[tid] = o;
}

// ---------------------------------------------------------------------------
// Fused MLP kernel. 256 threads = 4 waves; each wave owns 64 edges (4 M-tiles).
// L1: H1[64][128] = relu(gather @ W1 + b1) via mfma_16x16x32_bf16, K=256.
// H1 -> per-wave LDS tile [64][128] bf16, 16B-unit XOR swizzle (unit ^= row&7).
// L2: H2[64][64] = relu(H1 @ W2 + b2), A-frags via swizzled ds_read_b128.
// L3: out = H2 @ W3 + b3 via per-lane partial + 16-lane shfl_xor reduce.
// No block barriers: LDS regions are per-wave; explicit lgkmcnt(0) between
// the cross-lane LDS write and read.
// ---------------------------------------------------------------------------
__global__ __launch_bounds__(256, 2) void mlp_edge(
    const unsigned short* __restrict__ zb, const int* __restrict__ edge,
    const unsigned short* __restrict__ fw1, const unsigned short* __restrict__ fw2,
    const float* __restrict__ b1, const float* __restrict__ b2,
    const float* __restrict__ W3, const float* __restrict__ b3,
    float* __restrict__ out) {
  __shared__ __align__(16) unsigned short h1[4][64][128];  // 64 KB exactly
  const int l = threadIdx.x & 63, w = threadIdx.x >> 6;
  const int wt = blockIdx.x * 4 + w;
  if (wt >= NWT) return;
  const int c = l & 15, g = l >> 4;
  const int eBase = wt * 64;

  // node byte-offsets into bf16 z (row = 256 B)
  unsigned srcO[4], dstO[4];
#pragma unroll
  for (int mt = 0; mt < 4; mt++) {
    int e = eBase + mt * 16 + c;          // A-frag row for this lane, tile mt
    srcO[mt] = (unsigned)edge[e] * 256u;
    dstO[mt] = (unsigned)edge[NE + e] * 256u;
  }
  const char* zbase = (const char*)zb;

  // ---- Layer 1: K = 256 (kb 0..3 -> src half, 4..7 -> dst half) ----
  f32x4 acc[4][8] = {};
#pragma unroll
  for (int kb = 0; kb < 8; kb++) {
    const unsigned koff = ((unsigned)(kb & 3) * 32u + (unsigned)g * 8u) * 2u;  // bytes
    bf16x8 af[4];
#pragma unroll
    for (int mt = 0; mt < 4; mt++) {
      const unsigned ro = (kb < 4) ? srcO[mt] : dstO[mt];
      af[mt] = *(const bf16x8*)(zbase + ro + koff);
    }
#pragma unroll
    for (int nt = 0; nt < 8; nt++) {
      bf16x8 bf = *(const bf16x8*)(fw1 + ((nt * 8 + kb) * 64 + l) * 8);
#pragma unroll
      for (int mt = 0; mt < 4; mt++)
        acc[mt][nt] = __builtin_amdgcn_mfma_f32_16x16x32_bf16(af[mt], bf, acc[mt][nt], 0, 0, 0);
    }
  }

  // ---- bias + relu -> swizzled LDS (C/D layout: row=(l>>4)*4+i, col=l&15) ----
  float b1v[8];
#pragma unroll
  for (int nt = 0; nt < 8; nt++) b1v[nt] = b1[nt * 16 + c];
  const int c8 = c >> 3, c7 = c & 7;
#pragma unroll
  for (int mt = 0; mt < 4; mt++) {
#pragma unroll
    for (int i = 0; i < 4; i++) {
      const int row = mt * 16 + g * 4 + i;
      const int swz = (g * 4 + i) & 7;  // row & 7
#pragma unroll
      for (int nt = 0; nt < 8; nt++) {
        float v = fmaxf(acc[mt][nt][i] + b1v[nt], 0.f);
        h1[w][row][(((nt * 2 + c8) ^ swz) << 3) + c7] = f2bf(v);
      }
    }
  }
  // cross-lane LDS RAW within the wave: drain LDS queue explicitly
  asm volatile("s_waitcnt lgkmcnt(0)" ::: "memory");

  // ---- Layer 2: K = 128 ----
  f32x4 acc2[4][4] = {};
#pragma unroll
  for (int kb = 0; kb < 4; kb++) {
    bf16x8 a2[4];
#pragma unroll
    for (int mt = 0; mt < 4; mt++) {
      // A row = mt*16 + c; unit = kb*4 + g; same XOR as write side
      a2[mt] = *(const bf16x8*)&h1[w][mt * 16 + c][((kb * 4 + g) ^ c7) << 3];
    }
#pragma unroll
    for (int nt = 0; nt < 4; nt++) {
      bf16x8 bf = *(const bf16x8*)(fw2 + ((nt * 4 + kb) * 64 + l) * 8);
#pragma unroll
      for (int mt = 0; mt < 4; mt++)
        acc2[mt][nt] = __builtin_amdgcn_mfma_f32_16x16x32_bf16(a2[mt], bf, acc2[mt][nt], 0, 0, 0);
    }
  }

  // ---- Layer 3: relu(H2 + b2) . W3 + b3, fp32 on VALU ----
  float w3v[4], b2v[4];
#pragma unroll
  for (int nt = 0; nt < 4; nt++) {
    w3v[nt] = W3[nt * 16 + c];
    b2v[nt] = b2[nt * 16 + c];
  }
  const float bias3 = b3[0];
  float s[4][4];
#pragma unroll
  for (int mt = 0; mt < 4; mt++) {
#pragma unroll
    for (int i = 0; i < 4; i++) {
      float t = 0.f;
#pragma unroll
      for (int nt = 0; nt < 4; nt++)
        t += fmaxf(acc2[mt][nt][i] + b2v[nt], 0.f) * w3v[nt];
      // reduce across the 16 lanes (c) of this lane-group
      t += __shfl_xor(t, 1);
      t += __shfl_xor(t, 2);
      t += __shfl_xor(t, 4);
      t += __shfl_xor(t, 8);
      s[mt][i] = t + bias3;
    }
  }
  if (c == 0) {
#pragma unroll
    for (int mt = 0; mt < 4; mt++)
#pragma unroll
      for (int i = 0; i < 4; i++)
        out[eBase + mt * 16 + g * 4 + i] = s[mt][i];
  }
}

extern "C" void kernel_launch(void* const* d_in, const int* in_sizes, int n_in,
                              void* d_out, int out_size, void* d_ws, size_t ws_size,
                              hipStream_t stream) {
  const float* z  = (const float*)d_in[0];
  const int* edge = (const int*)d_in[1];   // jax default x64-off -> int32
  const float* W1 = (const float*)d_in[2];
  const float* b1 = (const float*)d_in[3];
  const float* W2 = (const float*)d_in[4];
  const float* b2 = (const float*)d_in[5];
  const float* W3 = (const float*)d_in[6];
  const float* b3 = (const float*)d_in[7];
  float* out = (float*)d_out;

  unsigned short* fw1 = (unsigned short*)d_ws;  // 64 KB of W1 frags
  unsigned short* fw2 = fw1 + 32768;            // 16 KB of W2 frags
  unsigned short* zb  = fw2 + 8192;             // 25.6 MB bf16 z

  prep_weights<<<160, 256, 0, stream>>>(W1, W2, fw1, fw2);
  prep_z<<<(NN * 32 + 255) / 256, 256, 0, stream>>>((const float4*)z, (ushort4*)zb);

  const int nblocks = (NWT + 3) / 4;  // 3907
  mlp_edge<<<nblocks, 256, 0, stream>>>(zb, edge, fw1, fw2, b1, b2, W3, b3, out);
}

// Round 2
// 280.673 us; speedup vs baseline: 1.1013x; 1.1013x over previous
//
#include <hip/hip_runtime.h>
#include <hip/hip_bf16.h>

#define NE 1000000
#define NN 100000
#define NWT 31250  // NE / 32 edges per wave-tile

typedef __attribute__((ext_vector_type(8))) short bf16x8;
typedef __attribute__((ext_vector_type(8))) short short8;
typedef __attribute__((ext_vector_type(4))) float f32x4;

__device__ __forceinline__ unsigned short f2bf(float f) {
  // round-to-nearest-even f32 -> bf16
  unsigned u = __builtin_bit_cast(unsigned, f);
  u += 0x7fffu + ((u >> 16) & 1u);
  return (unsigned short)(u >> 16);
}

// ---------------------------------------------------------------------------
// Fused prep: (a) z f32 -> bf16, 8 elem/thread; (b) swizzle W1/W2 into MFMA
// B-fragment order: frag (nt, kb): lane l holds B[kb*32+(l>>4)*8+j][nt*16+(l&15)]
// at fw[((nt*NKB+kb)*64+l)*8+j] -> per-lane 16B contiguous, wave-coalesced.
// ---------------------------------------------------------------------------
__global__ void prep(const float* __restrict__ W1, const float* __restrict__ W2,
                     const float4* __restrict__ z4,
                     unsigned short* __restrict__ fw1, unsigned short* __restrict__ fw2,
                     short8* __restrict__ zb8) {
  int tid = blockIdx.x * 256 + threadIdx.x;
  if (tid < NN * 16) {  // 1.6e6 threads, 8 f32 each
    float4 a = z4[tid * 2], b = z4[tid * 2 + 1];
    short8 o;
    o[0] = f2bf(a.x); o[1] = f2bf(a.y); o[2] = f2bf(a.z); o[3] = f2bf(a.w);
    o[4] = f2bf(b.x); o[5] = f2bf(b.y); o[6] = f2bf(b.z); o[7] = f2bf(b.w);
    zb8[tid] = o;
  }
  if (tid < 32768) {  // W1: [256][128], 8 n-tiles x 8 k-blocks
    int j = tid & 7, l = (tid >> 3) & 63, kb = (tid >> 9) & 7, nt = tid >> 12;
    fw1[tid] = f2bf(W1[(kb * 32 + (l >> 4) * 8 + j) * 128 + nt * 16 + (l & 15)]);
  } else if (tid < 40960) {  // W2: [128][64], 4 n-tiles x 4 k-blocks
    int t = tid - 32768;
    int j = t & 7, l = (t >> 3) & 63, kb = (t >> 9) & 3, nt = t >> 11;
    fw2[t] = f2bf(W2[(kb * 32 + (l >> 4) * 8 + j) * 64 + nt * 16 + (l & 15)]);
  }
}

// ---------------------------------------------------------------------------
// Fused MLP. 256 threads = 4 waves; each wave owns 32 edges (2 M-tiles).
// 32 KB LDS/block + <=128 VGPR (__launch_bounds__(256,4)) -> 4 blocks/CU,
// 16 waves/CU: double the latency hiding of R1 (LDS was the occupancy binder).
// L1: H1[32][128] = relu(gather @ W1 + b1), mfma_16x16x32_bf16, K=256.
// H1 -> per-wave LDS tile [32][128] bf16, 16B-unit XOR swizzle (unit ^= row&7).
// L2: H2[32][64] = relu(H1 @ W2 + b2), A-frags via swizzled ds_read_b128.
// L3: out = H2 @ W3 + b3 via 16-lane shfl_xor reduce. No block barriers
// (per-wave LDS regions + explicit lgkmcnt(0)).
// ---------------------------------------------------------------------------
__global__ __launch_bounds__(256, 4) void mlp_edge(
    const unsigned short* __restrict__ zb, const int* __restrict__ edge,
    const unsigned short* __restrict__ fw1, const unsigned short* __restrict__ fw2,
    const float* __restrict__ b1, const float* __restrict__ b2,
    const float* __restrict__ W3, const float* __restrict__ b3,
    float* __restrict__ out) {
  __shared__ __align__(16) unsigned short h1[4][32][128];  // 32 KB
  const int l = threadIdx.x & 63, w = threadIdx.x >> 6;
  const int wt = blockIdx.x * 4 + w;
  if (wt >= NWT) return;
  const int c = l & 15, g = l >> 4;
  const int eBase = wt * 32;

  // node byte-offsets into bf16 z (row = 256 B)
  unsigned srcO[2], dstO[2];
#pragma unroll
  for (int mt = 0; mt < 2; mt++) {
    int e = eBase + mt * 16 + c;  // A-frag row for this lane, tile mt
    srcO[mt] = (unsigned)edge[e] * 256u;
    dstO[mt] = (unsigned)edge[NE + e] * 256u;
  }
  const char* zbase = (const char*)zb;

  // ---- Layer 1: K = 256 (kb 0..3 -> src half, 4..7 -> dst half) ----
  f32x4 acc[2][8] = {};
#pragma unroll
  for (int kb = 0; kb < 8; kb++) {
    const unsigned koff = ((unsigned)(kb & 3) * 32u + (unsigned)g * 8u) * 2u;  // bytes
    bf16x8 af[2];
#pragma unroll
    for (int mt = 0; mt < 2; mt++) {
      const unsigned ro = (kb < 4) ? srcO[mt] : dstO[mt];
      af[mt] = *(const bf16x8*)(zbase + ro + koff);
    }
#pragma unroll
    for (int nt = 0; nt < 8; nt++) {
      bf16x8 bf = *(const bf16x8*)(fw1 + ((nt * 8 + kb) * 64 + l) * 8);
#pragma unroll
      for (int mt = 0; mt < 2; mt++)
        acc[mt][nt] = __builtin_amdgcn_mfma_f32_16x16x32_bf16(af[mt], bf, acc[mt][nt], 0, 0, 0);
    }
  }

  // ---- bias + relu -> swizzled LDS (C/D layout: row=(l>>4)*4+i, col=l&15) ----
  float b1v[8];
#pragma unroll
  for (int nt = 0; nt < 8; nt++) b1v[nt] = b1[nt * 16 + c];
  const int c8 = c >> 3, c7 = c & 7;
#pragma unroll
  for (int mt = 0; mt < 2; mt++) {
#pragma unroll
    for (int i = 0; i < 4; i++) {
      const int row = mt * 16 + g * 4 + i;
      const int swz = (g * 4 + i) & 7;  // row & 7
#pragma unroll
      for (int nt = 0; nt < 8; nt++) {
        float v = fmaxf(acc[mt][nt][i] + b1v[nt], 0.f);
        h1[w][row][(((nt * 2 + c8) ^ swz) << 3) + c7] = f2bf(v);
      }
    }
  }
  // cross-lane LDS RAW within the wave: drain LDS queue explicitly
  asm volatile("s_waitcnt lgkmcnt(0)" ::: "memory");

  // ---- Layer 2: K = 128 ----
  f32x4 acc2[2][4] = {};
#pragma unroll
  for (int kb = 0; kb < 4; kb++) {
    bf16x8 a2[2];
#pragma unroll
    for (int mt = 0; mt < 2; mt++) {
      // A row = mt*16 + c; unit = kb*4 + g; same XOR as write side
      a2[mt] = *(const bf16x8*)&h1[w][mt * 16 + c][((kb * 4 + g) ^ c7) << 3];
    }
#pragma unroll
    for (int nt = 0; nt < 4; nt++) {
      bf16x8 bf = *(const bf16x8*)(fw2 + ((nt * 4 + kb) * 64 + l) * 8);
#pragma unroll
      for (int mt = 0; mt < 2; mt++)
        acc2[mt][nt] = __builtin_amdgcn_mfma_f32_16x16x32_bf16(a2[mt], bf, acc2[mt][nt], 0, 0, 0);
    }
  }

  // ---- Layer 3: relu(H2 + b2) . W3 + b3, fp32 on VALU ----
  float w3v[4], b2v[4];
#pragma unroll
  for (int nt = 0; nt < 4; nt++) {
    w3v[nt] = W3[nt * 16 + c];
    b2v[nt] = b2[nt * 16 + c];
  }
  const float bias3 = b3[0];
  float s[2][4];
#pragma unroll
  for (int mt = 0; mt < 2; mt++) {
#pragma unroll
    for (int i = 0; i < 4; i++) {
      float t = 0.f;
#pragma unroll
      for (int nt = 0; nt < 4; nt++)
        t += fmaxf(acc2[mt][nt][i] + b2v[nt], 0.f) * w3v[nt];
      // reduce across the 16 lanes (c) of this lane-group
      t += __shfl_xor(t, 1);
      t += __shfl_xor(t, 2);
      t += __shfl_xor(t, 4);
      t += __shfl_xor(t, 8);
      s[mt][i] = t + bias3;
    }
  }
  if (c == 0) {
#pragma unroll
    for (int mt = 0; mt < 2; mt++)
#pragma unroll
      for (int i = 0; i < 4; i++)
        out[eBase + mt * 16 + g * 4 + i] = s[mt][i];
  }
}

extern "C" void kernel_launch(void* const* d_in, const int* in_sizes, int n_in,
                              void* d_out, int out_size, void* d_ws, size_t ws_size,
                              hipStream_t stream) {
  const float* z  = (const float*)d_in[0];
  const int* edge = (const int*)d_in[1];   // jax default x64-off -> int32
  const float* W1 = (const float*)d_in[2];
  const float* b1 = (const float*)d_in[3];
  const float* W2 = (const float*)d_in[4];
  const float* b2 = (const float*)d_in[5];
  const float* W3 = (const float*)d_in[6];
  const float* b3 = (const float*)d_in[7];
  float* out = (float*)d_out;

  unsigned short* fw1 = (unsigned short*)d_ws;  // 64 KB of W1 frags
  unsigned short* fw2 = fw1 + 32768;            // 16 KB of W2 frags
  unsigned short* zb  = fw2 + 8192;             // 25.6 MB bf16 z

  prep<<<(NN * 16 + 255) / 256, 256, 0, stream>>>(W1, W2, (const float4*)z,
                                                  fw1, fw2, (short8*)zb);

  const int nblocks = (NWT + 3) / 4;  // 7813
  mlp_edge<<<nblocks, 256, 0, stream>>>(zb, edge, fw1, fw2, b1, b2, W3, b3, out);
}

// Round 3
// 206.501 us; speedup vs baseline: 1.4968x; 1.3592x over previous
//
#include <hip/hip_runtime.h>
#include <hip/hip_bf16.h>

#define NE 1000000
#define NN 100000
#define NWT 31250   // edges / 32 per wave-tile
#define NGT 6250    // nodes / 16 per wave-tile

typedef __attribute__((ext_vector_type(8))) short bf16x8;
typedef __attribute__((ext_vector_type(4))) float f32x4;

__device__ __forceinline__ unsigned short f2bf(float f) {
  // round-to-nearest-even f32 -> bf16
  unsigned u = __builtin_bit_cast(unsigned, f);
  u += 0x7fffu + ((u >> 16) & 1u);
  return (unsigned short)(u >> 16);
}
__device__ __forceinline__ float bf2f(unsigned short s) {
  return __builtin_bit_cast(float, (unsigned)s << 16);
}

// ---------------------------------------------------------------------------
// Prep: build MFMA fragments for Wcat^T (A-operand of node_gemm) and W2
// (B-operand of edge kernel). Wcat = [W1a | W1b] : [128][256],
//   Wcat[k][n] = n<128 ? W1[k][n] : W1[128+k][n-128].
// A-frag(mt,kb): lane l, j: Wcat[kb*32+(l>>4)*8+j][mt*16+(l&15)]  (16 mt, 4 kb)
// B-frag(nt,kb): lane l, j: W2[kb*32+(l>>4)*8+j][nt*16+(l&15)]    (4 nt, 4 kb)
// ---------------------------------------------------------------------------
__global__ void prep(const float* __restrict__ W1, const float* __restrict__ W2,
                     unsigned short* __restrict__ afw, unsigned short* __restrict__ fw2) {
  int tid = blockIdx.x * 256 + threadIdx.x;
  if (tid < 32768) {
    int j = tid & 7, l = (tid >> 3) & 63, kb = (tid >> 9) & 3, mt = tid >> 11;
    int k = kb * 32 + (l >> 4) * 8 + j;   // 0..127
    int n = mt * 16 + (l & 15);           // 0..255
    float v = (n < 128) ? W1[k * 128 + n] : W1[(128 + k) * 128 + (n - 128)];
    afw[tid] = f2bf(v);
  } else if (tid < 40960) {
    int t = tid - 32768;
    int j = t & 7, l = (t >> 3) & 63, kb = (t >> 9) & 3, nt = t >> 11;
    fw2[t] = f2bf(W2[(kb * 32 + (l >> 4) * 8 + j) * 64 + nt * 16 + (l & 15)]);
  }
}

// ---------------------------------------------------------------------------
// Per-node precompute: h1ab[n][0:128] = z[n]@W1a + b1 ; h1ab[n][128:256] = z[n]@W1b
// Swapped-operand MFMA: A = Wcat^T frags (features = M), B = z rows (nodes = N).
// D layout: col = lane&15 = node, row = (lane>>4)*4+i = feature -> each lane
// holds 4 CONSECUTIVE features of one node: packed 8 B bf16 store, no transpose.
// One wave = 16 nodes, all 256 features. 6.6 GF total.
// ---------------------------------------------------------------------------
__global__ __launch_bounds__(256, 4) void node_gemm(
    const float* __restrict__ z, const unsigned short* __restrict__ afw,
    const float* __restrict__ b1, unsigned short* __restrict__ h1ab) {
  const int l = threadIdx.x & 63, w = threadIdx.x >> 6;
  const int wtile = blockIdx.x * 4 + w;
  if (wtile >= NGT) return;
  const int c = l & 15, g = l >> 4;
  const int node0 = wtile * 16;

  f32x4 acc[16] = {};
#pragma unroll
  for (int kb = 0; kb < 4; kb++) {
    const float* zp = z + (node0 + c) * 128 + kb * 32 + g * 8;
    float4 z0 = *(const float4*)zp;
    float4 z1 = *(const float4*)(zp + 4);
    bf16x8 bfrag;
    bfrag[0] = f2bf(z0.x); bfrag[1] = f2bf(z0.y); bfrag[2] = f2bf(z0.z); bfrag[3] = f2bf(z0.w);
    bfrag[4] = f2bf(z1.x); bfrag[5] = f2bf(z1.y); bfrag[6] = f2bf(z1.z); bfrag[7] = f2bf(z1.w);
#pragma unroll
    for (int mt = 0; mt < 16; mt++) {
      bf16x8 af = *(const bf16x8*)(afw + ((mt * 4 + kb) * 64 + l) * 8);
      acc[mt] = __builtin_amdgcn_mfma_f32_16x16x32_bf16(af, bfrag, acc[mt], 0, 0, 0);
    }
  }
  // epilogue: +b1 on the a-half (features < 128), pack 4 bf16, 8 B store
#pragma unroll
  for (int mt = 0; mt < 16; mt++) {
    const int f0 = mt * 16 + g * 4;
    float v0 = acc[mt][0], v1 = acc[mt][1], v2 = acc[mt][2], v3 = acc[mt][3];
    if (mt < 8) {  // f0+3 <= 127 here
      float4 bb = *(const float4*)(b1 + f0);
      v0 += bb.x; v1 += bb.y; v2 += bb.z; v3 += bb.w;
    }
    unsigned lo = (unsigned)f2bf(v0) | ((unsigned)f2bf(v1) << 16);
    unsigned hi = (unsigned)f2bf(v2) | ((unsigned)f2bf(v3) << 16);
    uint2 pk = {lo, hi};
    *(uint2*)(h1ab + (node0 + c) * 256 + f0) = pk;
  }
}

// ---------------------------------------------------------------------------
// Edge kernel. 4 waves/block, 32 edges/wave (2 M-tiles).
// h1 = relu(h1ab[src][0:128] + h1ab[dst][128:256]) built lane-local directly
// in MFMA A-layout (no LDS, no transpose). Layer 2 via mfma, B-frags from a
// 16 KB LDS copy of fw2 (so the gather stream can't thrash them out of L1).
// Layer 3 = 16-lane shfl_xor reduce. Each gather instr consumes 16 FULL 64 B
// lines (4 g-chunks per line).
// ---------------------------------------------------------------------------
__global__ __launch_bounds__(256, 5) void mlp_edge(
    const unsigned short* __restrict__ h1ab, const int* __restrict__ edge,
    const unsigned short* __restrict__ fw2,
    const float* __restrict__ b2, const float* __restrict__ W3,
    const float* __restrict__ b3, float* __restrict__ out) {
  __shared__ __align__(16) unsigned short sfw2[8192];  // 16 KB
  {
    const int t = threadIdx.x;
#pragma unroll
    for (int it = 0; it < 4; it++)
      ((bf16x8*)sfw2)[it * 256 + t] = ((const bf16x8*)fw2)[it * 256 + t];
  }
  __syncthreads();  // before any wave can early-exit

  const int l = threadIdx.x & 63, w = threadIdx.x >> 6;
  const int wt = blockIdx.x * 4 + w;
  if (wt >= NWT) return;
  const int c = l & 15, g = l >> 4;
  const int eBase = wt * 32;

  unsigned srcO[2], dstO[2];
#pragma unroll
  for (int mt = 0; mt < 2; mt++) {
    int e = eBase + mt * 16 + c;  // this lane's A-row for tile mt
    srcO[mt] = (unsigned)edge[e] * 512u;
    dstO[mt] = (unsigned)edge[NE + e] * 512u + 256u;
  }
  const char* hb = (const char*)h1ab;
  const unsigned kbase = (unsigned)g * 16u;

  f32x4 acc2[2][4] = {};
#pragma unroll
  for (int kb = 0; kb < 4; kb++) {
    const unsigned koff = (unsigned)kb * 64u + kbase;
    bf16x8 a2[2];
#pragma unroll
    for (int mt = 0; mt < 2; mt++) {
      bf16x8 ha = *(const bf16x8*)(hb + srcO[mt] + koff);
      bf16x8 hd = *(const bf16x8*)(hb + dstO[mt] + koff);
#pragma unroll
      for (int j = 0; j < 8; j++) {
        float v = bf2f((unsigned short)ha[j]) + bf2f((unsigned short)hd[j]);
        a2[mt][j] = (short)f2bf(fmaxf(v, 0.f));
      }
    }
#pragma unroll
    for (int nt = 0; nt < 4; nt++) {
      bf16x8 bf = ((const bf16x8*)sfw2)[(nt * 4 + kb) * 64 + l];
#pragma unroll
      for (int mt = 0; mt < 2; mt++)
        acc2[mt][nt] = __builtin_amdgcn_mfma_f32_16x16x32_bf16(a2[mt], bf, acc2[mt][nt], 0, 0, 0);
    }
  }

  // ---- Layer 3: relu(H2 + b2) . W3 + b3 ----
  float w3v[4], b2v[4];
#pragma unroll
  for (int nt = 0; nt < 4; nt++) {
    w3v[nt] = W3[nt * 16 + c];
    b2v[nt] = b2[nt * 16 + c];
  }
  const float bias3 = b3[0];
#pragma unroll
  for (int mt = 0; mt < 2; mt++) {
#pragma unroll
    for (int i = 0; i < 4; i++) {
      float t = 0.f;
#pragma unroll
      for (int nt = 0; nt < 4; nt++)
        t += fmaxf(acc2[mt][nt][i] + b2v[nt], 0.f) * w3v[nt];
      t += __shfl_xor(t, 1);
      t += __shfl_xor(t, 2);
      t += __shfl_xor(t, 4);
      t += __shfl_xor(t, 8);
      if (c == 0) out[eBase + mt * 16 + g * 4 + i] = t + bias3;
    }
  }
}

extern "C" void kernel_launch(void* const* d_in, const int* in_sizes, int n_in,
                              void* d_out, int out_size, void* d_ws, size_t ws_size,
                              hipStream_t stream) {
  const float* z  = (const float*)d_in[0];
  const int* edge = (const int*)d_in[1];   // jax x64 off -> int32
  const float* W1 = (const float*)d_in[2];
  const float* b1 = (const float*)d_in[3];
  const float* W2 = (const float*)d_in[4];
  const float* b2 = (const float*)d_in[5];
  const float* W3 = (const float*)d_in[6];
  const float* b3 = (const float*)d_in[7];
  float* out = (float*)d_out;

  unsigned short* afw  = (unsigned short*)d_ws;       // 64 KB  Wcat^T A-frags
  unsigned short* fw2  = afw + 32768;                 // 16 KB  W2 B-frags
  unsigned short* h1ab = fw2 + 8192;                  // 51.2 MB per-node partials

  prep<<<160, 256, 0, stream>>>(W1, W2, afw, fw2);
  node_gemm<<<(NGT + 3) / 4, 256, 0, stream>>>(z, afw, b1, h1ab);
  mlp_edge<<<(NWT + 3) / 4, 256, 0, stream>>>(h1ab, edge, fw2, b2, W3, b3, out);
}

// Round 5
// 204.804 us; speedup vs baseline: 1.5092x; 1.0083x over previous
//
#include <hip/hip_runtime.h>
#include <hip/hip_bf16.h>
#include <string.h>

#define NE 1000000
#define NN 100000
#define NWT 31250   // edges / 32 per wave-tile
#define NGT2 3125   // nodes / 32 per wave-tile

typedef __attribute__((ext_vector_type(8))) short bf16x8;
typedef __attribute__((ext_vector_type(4))) float f32x4;

__device__ __forceinline__ unsigned short f2bf(float f) {
  // round-to-nearest-even f32 -> bf16 (prep only)
  unsigned u = __builtin_bit_cast(unsigned, f);
  u += 0x7fffu + ((u >> 16) & 1u);
  return (unsigned short)(u >> 16);
}
// packed pair: low16 = bf16(a) (elem 2i), high16 = bf16(b) (elem 2i+1)
__device__ __forceinline__ unsigned pk2(float a, float b) {
  __hip_bfloat162 h = __float22bfloat162_rn(make_float2(a, b));
  unsigned r;
  memcpy(&r, &h, 4);  // __hip_bfloat162 not trivially copyable -> no bit_cast
  return r;
}
__device__ __forceinline__ float lo2f(unsigned u) {
  return __builtin_bit_cast(float, u << 16);
}
__device__ __forceinline__ float hi2f(unsigned u) {
  return __builtin_bit_cast(float, u & 0xffff0000u);
}

// ---------------------------------------------------------------------------
// Prep: MFMA fragments for Wcat^T (A-operand of node_gemm) and W2 (B-operand
// of edge kernel). Wcat = [W1a | W1b] : [128][256].
// A-frag(mt,kb): lane l, j: Wcat[kb*32+(l>>4)*8+j][mt*16+(l&15)]  (16 mt, 4 kb)
// B-frag(nt,kb): lane l, j: W2[kb*32+(l>>4)*8+j][nt*16+(l&15)]    (4 nt, 4 kb)
// ---------------------------------------------------------------------------
__global__ void prep(const float* __restrict__ W1, const float* __restrict__ W2,
                     unsigned short* __restrict__ afw, unsigned short* __restrict__ fw2) {
  int tid = blockIdx.x * 256 + threadIdx.x;
  if (tid < 32768) {
    int j = tid & 7, l = (tid >> 3) & 63, kb = (tid >> 9) & 3, mt = tid >> 11;
    int k = kb * 32 + (l >> 4) * 8 + j;   // 0..127
    int n = mt * 16 + (l & 15);           // 0..255
    float v = (n < 128) ? W1[k * 128 + n] : W1[(128 + k) * 128 + (n - 128)];
    afw[tid] = f2bf(v);
  } else if (tid < 40960) {
    int t = tid - 32768;
    int j = t & 7, l = (t >> 3) & 63, kb = (t >> 9) & 3, nt = t >> 11;
    fw2[t] = f2bf(W2[(kb * 32 + (l >> 4) * 8 + j) * 64 + nt * 16 + (l & 15)]);
  }
}

// ---------------------------------------------------------------------------
// Per-node precompute: h1ab[n][0:128] = z[n]@W1a + b1 ; h1ab[n][128:256] = z[n]@W1b
// Swapped-operand MFMA: A = Wcat^T frags (features = M), B = z rows (nodes).
// Each wave: 32 nodes (2 B-frag groups sharing every A-frag ds_read).
// afw staged once per block in LDS (64 KB); all 16 z float4-loads hoisted.
// D layout: col = node, row = feature -> lane holds 4 consecutive features of
// one node: packed 8 B bf16 store, no transpose.
// ---------------------------------------------------------------------------
__global__ __launch_bounds__(256, 2) void node_gemm(
    const float* __restrict__ z, const unsigned short* __restrict__ afw,
    const float* __restrict__ b1, unsigned short* __restrict__ h1ab) {
  __shared__ __align__(16) bf16x8 sfw[4096];  // 64 KB
  {
    const int t = threadIdx.x;
#pragma unroll
    for (int it = 0; it < 16; it++)
      sfw[it * 256 + t] = ((const bf16x8*)afw)[it * 256 + t];
  }
  __syncthreads();

  const int l = threadIdx.x & 63, w = threadIdx.x >> 6;
  const int wt = blockIdx.x * 4 + w;
  if (wt >= NGT2) return;
  const int c = l & 15, g = l >> 4;
  const int n0 = wt * 32;

  // hoist all z loads: 2 groups x 4 kb x 2 float4
  float4 zl[2][4][2];
#pragma unroll
  for (int grp = 0; grp < 2; grp++)
#pragma unroll
    for (int kb = 0; kb < 4; kb++) {
      const float* zp = z + (n0 + grp * 16 + c) * 128 + kb * 32 + g * 8;
      zl[grp][kb][0] = *(const float4*)zp;
      zl[grp][kb][1] = *(const float4*)(zp + 4);
    }

  f32x4 acc[2][16] = {};
#pragma unroll
  for (int kb = 0; kb < 4; kb++) {
    bf16x8 bfrag[2];
#pragma unroll
    for (int grp = 0; grp < 2; grp++) {
      float4 a = zl[grp][kb][0], b = zl[grp][kb][1];
      uint4 u = {pk2(a.x, a.y), pk2(a.z, a.w), pk2(b.x, b.y), pk2(b.z, b.w)};
      bfrag[grp] = __builtin_bit_cast(bf16x8, u);
    }
#pragma unroll
    for (int mt = 0; mt < 16; mt++) {
      bf16x8 af = sfw[(mt * 4 + kb) * 64 + l];
      acc[0][mt] = __builtin_amdgcn_mfma_f32_16x16x32_bf16(af, bfrag[0], acc[0][mt], 0, 0, 0);
      acc[1][mt] = __builtin_amdgcn_mfma_f32_16x16x32_bf16(af, bfrag[1], acc[1][mt], 0, 0, 0);
    }
  }

  // epilogue: +b1 on features < 128, pack 4 bf16, 8 B store per (grp, mt)
#pragma unroll
  for (int grp = 0; grp < 2; grp++)
#pragma unroll
    for (int mt = 0; mt < 16; mt++) {
      const int f0 = mt * 16 + g * 4;
      float v0 = acc[grp][mt][0], v1 = acc[grp][mt][1];
      float v2 = acc[grp][mt][2], v3 = acc[grp][mt][3];
      if (mt < 8) {
        float4 bb = *(const float4*)(b1 + f0);
        v0 += bb.x; v1 += bb.y; v2 += bb.z; v3 += bb.w;
      }
      uint2 pk = {pk2(v0, v1), pk2(v2, v3)};
      *(uint2*)(h1ab + (n0 + grp * 16 + c) * 256 + f0) = pk;
    }
}

// ---------------------------------------------------------------------------
// Edge kernel. 4 waves/block, 32 edges/wave (2 M-tiles).
// All 16 gather loads (uint4) hoisted up front -> one latency exposure per
// wave-tile. h1 = relu(ha+hb) built lane-local in MFMA A-layout via
// shift-unpack + v_cvt_pk_bf16_f32 repack. Layer 2 B-frags from 16 KB LDS.
// Layer 3 = 16-lane shfl_xor reduce.
// ---------------------------------------------------------------------------
__global__ __launch_bounds__(256, 4) void mlp_edge(
    const unsigned short* __restrict__ h1ab, const int* __restrict__ edge,
    const unsigned short* __restrict__ fw2,
    const float* __restrict__ b2, const float* __restrict__ W3,
    const float* __restrict__ b3, float* __restrict__ out) {
  __shared__ __align__(16) unsigned short sfw2[8192];  // 16 KB
  {
    const int t = threadIdx.x;
#pragma unroll
    for (int it = 0; it < 4; it++)
      ((bf16x8*)sfw2)[it * 256 + t] = ((const bf16x8*)fw2)[it * 256 + t];
  }
  __syncthreads();  // before any wave can early-exit

  const int l = threadIdx.x & 63, w = threadIdx.x >> 6;
  const int wt = blockIdx.x * 4 + w;
  if (wt >= NWT) return;
  const int c = l & 15, g = l >> 4;
  const int eBase = wt * 32;

  const char* hb = (const char*)h1ab;
  const unsigned kbase = (unsigned)g * 16u;

  // hoist all 16 gathers: [mt][kb] for src and dst halves
  uint4 sv[2][4], dv[2][4];
#pragma unroll
  for (int mt = 0; mt < 2; mt++) {
    int e = eBase + mt * 16 + c;  // this lane's A-row for tile mt
    unsigned so = (unsigned)edge[e] * 512u + kbase;
    unsigned dofs = (unsigned)edge[NE + e] * 512u + 256u + kbase;
#pragma unroll
    for (int kb = 0; kb < 4; kb++) {
      sv[mt][kb] = *(const uint4*)(hb + so + kb * 64u);
      dv[mt][kb] = *(const uint4*)(hb + dofs + kb * 64u);
    }
  }

  f32x4 acc2[2][4] = {};
#pragma unroll
  for (int kb = 0; kb < 4; kb++) {
    bf16x8 a2[2];
#pragma unroll
    for (int mt = 0; mt < 2; mt++) {
      uint4 s = sv[mt][kb], d = dv[mt][kb];
      uint4 r;
      r.x = pk2(fmaxf(lo2f(s.x) + lo2f(d.x), 0.f), fmaxf(hi2f(s.x) + hi2f(d.x), 0.f));
      r.y = pk2(fmaxf(lo2f(s.y) + lo2f(d.y), 0.f), fmaxf(hi2f(s.y) + hi2f(d.y), 0.f));
      r.z = pk2(fmaxf(lo2f(s.z) + lo2f(d.z), 0.f), fmaxf(hi2f(s.z) + hi2f(d.z), 0.f));
      r.w = pk2(fmaxf(lo2f(s.w) + lo2f(d.w), 0.f), fmaxf(hi2f(s.w) + hi2f(d.w), 0.f));
      a2[mt] = __builtin_bit_cast(bf16x8, r);
    }
#pragma unroll
    for (int nt = 0; nt < 4; nt++) {
      bf16x8 bf = ((const bf16x8*)sfw2)[(nt * 4 + kb) * 64 + l];
#pragma unroll
      for (int mt = 0; mt < 2; mt++)
        acc2[mt][nt] = __builtin_amdgcn_mfma_f32_16x16x32_bf16(a2[mt], bf, acc2[mt][nt], 0, 0, 0);
    }
  }

  // ---- Layer 3: relu(H2 + b2) . W3 + b3 ----
  float w3v[4], b2v[4];
#pragma unroll
  for (int nt = 0; nt < 4; nt++) {
    w3v[nt] = W3[nt * 16 + c];
    b2v[nt] = b2[nt * 16 + c];
  }
  const float bias3 = b3[0];
#pragma unroll
  for (int mt = 0; mt < 2; mt++) {
#pragma unroll
    for (int i = 0; i < 4; i++) {
      float t = 0.f;
#pragma unroll
      for (int nt = 0; nt < 4; nt++)
        t += fmaxf(acc2[mt][nt][i] + b2v[nt], 0.f) * w3v[nt];
      t += __shfl_xor(t, 1);
      t += __shfl_xor(t, 2);
      t += __shfl_xor(t, 4);
      t += __shfl_xor(t, 8);
      if (c == 0) out[eBase + mt * 16 + g * 4 + i] = t + bias3;
    }
  }
}

extern "C" void kernel_launch(void* const* d_in, const int* in_sizes, int n_in,
                              void* d_out, int out_size, void* d_ws, size_t ws_size,
                              hipStream_t stream) {
  const float* z  = (const float*)d_in[0];
  const int* edge = (const int*)d_in[1];   // jax x64 off -> int32
  const float* W1 = (const float*)d_in[2];
  const float* b1 = (const float*)d_in[3];
  const float* W2 = (const float*)d_in[4];
  const float* b2 = (const float*)d_in[5];
  const float* W3 = (const float*)d_in[6];
  const float* b3 = (const float*)d_in[7];
  float* out = (float*)d_out;

  unsigned short* afw  = (unsigned short*)d_ws;       // 64 KB  Wcat^T A-frags
  unsigned short* fw2  = afw + 32768;                 // 16 KB  W2 B-frags
  unsigned short* h1ab = fw2 + 8192;                  // 51.2 MB per-node partials

  prep<<<160, 256, 0, stream>>>(W1, W2, afw, fw2);
  node_gemm<<<(NGT2 + 3) / 4, 256, 0, stream>>>(z, afw, b1, h1ab);
  mlp_edge<<<(NWT + 3) / 4, 256, 0, stream>>>(h1ab, edge, fw2, b2, W3, b3, out);
}